// Round 6
// baseline (344.753 us; speedup 1.0000x reference)
//
#include <hip/hip_runtime.h>
#include <hip/hip_bf16.h>
#include <stdint.h>

typedef __bf16 bf16_t;
typedef __bf16 bf16x4 __attribute__((ext_vector_type(4)));
typedef __bf16 bf16x8 __attribute__((ext_vector_type(8)));
typedef float f32x4 __attribute__((ext_vector_type(4)));

#define MFMA_16x16x32(A, B, C) __builtin_amdgcn_mfma_f32_16x16x32_bf16(A, B, C, 0, 0, 0)
#define EXP2(x) __builtin_amdgcn_exp2f(x)

static constexpr float kScale = 0.08838834764831845f;  // 1/sqrt(128)
static constexpr float kLog2e = 1.4426950408889634f;
static constexpr float kC1 = kScale * kLog2e;  // raw-score -> exp2 argument

// async global->LDS, 16B per lane; LDS dst is wave-uniform base + lane*16
__device__ __forceinline__ void lds_cp16(void* lds, const void* g) {
  __builtin_amdgcn_global_load_lds(
      (__attribute__((address_space(1))) void*)(uintptr_t)g,
      (__attribute__((address_space(3))) void*)(uintptr_t)lds, 16, 0, 0);
}

// Stage a [R rows x K cols] bf16 tile into chunked LDS: (r,k) -> (k>>5)*(R*32)+r*32+(k&31).
template <int R, int K>
__device__ __forceinline__ void stage_tile(bf16_t* lds, const bf16_t* g, int ldg, int tid) {
  constexpr int TOT = R * K;
  constexpr int CH = R * 32;
  constexpr int ITERS = TOT / 2048;  // 256 threads * 8 elems
  const int wave = tid >> 6;
#pragma unroll
  for (int i = 0; i < ITERS; ++i) {
    int linear = i * 2048 + tid * 8;
    int chunk = linear / CH;
    int rem = linear % CH;
    int r = rem >> 5;
    int c = rem & 31;
    lds_cp16(lds + i * 2048 + wave * 512, g + r * ldg + chunk * 32 + c);
  }
}

__device__ __forceinline__ bf16x8 frag_ld(const bf16_t* lds_chunk, int row, int lane) {
  return *(const bf16x8*)(lds_chunk + row * 32 + ((lane >> 4) << 3));
}

// ---------- elementwise f32 -> bf16 convert ----------
__global__ void cvt_kernel(const float* __restrict__ src, bf16_t* __restrict__ dst) {
  const int i = (blockIdx.x * 256 + threadIdx.x) * 4;
  float4 v = *(const float4*)&src[i];
  bf16x4 o;
  o[0] = (bf16_t)v.x;
  o[1] = (bf16_t)v.y;
  o[2] = (bf16_t)v.z;
  o[3] = (bf16_t)v.w;
  *(bf16x4*)&dst[i] = o;
}

// ---------- tiled transpose f32 src -> bf16 dst: src[mats][R][C] -> dst[mats][C][R] ----------
__global__ void transpose_f32_k(const float* __restrict__ src, bf16_t* __restrict__ dst, int R,
                                int C) {
  __shared__ alignas(16) bf16_t tile[64][72];
  const int t = threadIdx.x;
  const int mat = blockIdx.z;
  const int r0 = blockIdx.x * 64, c0 = blockIdx.y * 64;
  const float* s = src + (size_t)mat * R * C;
  bf16_t* d = dst + (size_t)mat * R * C;
  const int rl = t >> 3, cl = (t & 7) * 8;
#pragma unroll
  for (int half = 0; half < 2; ++half) {
    const int r = r0 + rl + half * 32;
    float4 a = *(const float4*)&s[(size_t)r * C + c0 + cl];
    float4 b = *(const float4*)&s[(size_t)r * C + c0 + cl + 4];
    tile[cl + 0][rl + half * 32] = (bf16_t)a.x;
    tile[cl + 1][rl + half * 32] = (bf16_t)a.y;
    tile[cl + 2][rl + half * 32] = (bf16_t)a.z;
    tile[cl + 3][rl + half * 32] = (bf16_t)a.w;
    tile[cl + 4][rl + half * 32] = (bf16_t)b.x;
    tile[cl + 5][rl + half * 32] = (bf16_t)b.y;
    tile[cl + 6][rl + half * 32] = (bf16_t)b.z;
    tile[cl + 7][rl + half * 32] = (bf16_t)b.w;
  }
  __syncthreads();
  const int cl2 = t >> 3, rl2 = (t & 7) * 8;
  *(bf16x8*)&d[(size_t)(c0 + cl2) * R + r0 + rl2] = *(const bf16x8*)&tile[cl2][rl2];
  *(bf16x8*)&d[(size_t)(c0 + cl2 + 32) * R + r0 + rl2] = *(const bf16x8*)&tile[cl2 + 32][rl2];
}

// ---------- projections, writing fragment-major Qf/Kf/Vf directly ----------
// Qf/Kf: [h][nt(256)][ks(4)][lane(64)][8]  (frag = q[nt*16+l15][ks*32+quad*8+j])
// Vf:    [h][mb(128)][es(8)][lane(64)][8]  (frag = v[mb*32+quad*8+j][es*16+l15])
__global__ __launch_bounds__(256, 2) void proj_kernel(const bf16_t* __restrict__ X,
                                                      const bf16_t* __restrict__ Wt,
                                                      const float* __restrict__ bq,
                                                      const float* __restrict__ bk,
                                                      const float* __restrict__ bv,
                                                      bf16_t* __restrict__ qkv) {
  __shared__ alignas(16) char smem[34816];  // As(8K)+Bs(8K) in loop; Ct[128][136] in epilogue
  bf16_t* As = (bf16_t*)smem;
  bf16_t* Bs = (bf16_t*)(smem + 8192);
  const int t = threadIdx.x, lane = t & 63, w = t >> 6;
  const int l15 = lane & 15, quad = lane >> 4;
  const int ntile = blockIdx.x, mat = blockIdx.y;
  const bf16_t* a0 = X + (size_t)ntile * 128 * 1024;
  const bf16_t* b0 = Wt + (size_t)mat * 131072;
  f32x4 acc[4][4] = {};
  const int rb = (w >> 1) * 64, cb = (w & 1) * 64;
  for (int k0 = 0; k0 < 1024; k0 += 32) {
    stage_tile<128, 32>(As, a0 + k0, 1024, t);
    stage_tile<128, 32>(Bs, b0 + k0, 1024, t);
    __syncthreads();
    bf16x8 af[4], bfr[4];
#pragma unroll
    for (int i = 0; i < 4; ++i) af[i] = frag_ld(As, rb + i * 16 + l15, lane);
#pragma unroll
    for (int j = 0; j < 4; ++j) bfr[j] = frag_ld(Bs, cb + j * 16 + l15, lane);
#pragma unroll
    for (int i = 0; i < 4; ++i)
#pragma unroll
      for (int j = 0; j < 4; ++j) acc[i][j] = MFMA_16x16x32(af[i], bfr[j], acc[i][j]);
    __syncthreads();
  }
  const int proj = mat >> 3, h = mat & 7;
  const float* bias = (proj == 0 ? bq : proj == 1 ? bk : bv) + h * 128;
  bf16_t* Ct = (bf16_t*)smem;  // safe: loop ended with __syncthreads
  bf16_t* dst = qkv + (size_t)proj * 4194304 + (size_t)h * 524288;
  if (proj < 2) {
    // n-major bounce [n][e], pitch 136 (keeps 16B alignment, breaks pow2 stride)
#pragma unroll
    for (int i = 0; i < 4; ++i)
#pragma unroll
      for (int j = 0; j < 4; ++j) {
        const int e = cb + j * 16 + l15;
        const float bval = bias[e];
#pragma unroll
        for (int r = 0; r < 4; ++r)
          Ct[(rb + i * 16 + quad * 4 + r) * 136 + e] = (bf16_t)(acc[i][j][r] + bval);
      }
    __syncthreads();
#pragma unroll
    for (int u = 0; u < 2; ++u) {
      const int nt = w * 2 + u;
#pragma unroll
      for (int ks = 0; ks < 4; ++ks) {
        bf16x8 f = *(const bf16x8*)&Ct[(nt * 16 + l15) * 136 + ks * 32 + quad * 8];
        *(bf16x8*)&dst[(((size_t)(ntile * 8 + nt)) * 4 + ks) * 512 + lane * 8] = f;
      }
    }
  } else {
    // e-major bounce [e][m] (m = this block's n rows), b64 writes / b128 reads
#pragma unroll
    for (int i = 0; i < 4; ++i)
#pragma unroll
      for (int j = 0; j < 4; ++j) {
        const int e = cb + j * 16 + l15;
        const float bval = bias[e];
        bf16x4 pv;
#pragma unroll
        for (int r = 0; r < 4; ++r) pv[r] = (bf16_t)(acc[i][j][r] + bval);
        *(bf16x4*)&Ct[e * 136 + rb + i * 16 + quad * 4] = pv;
      }
    __syncthreads();
#pragma unroll
    for (int es = 0; es < 8; ++es) {
      bf16x8 f = *(const bf16x8*)&Ct[(es * 16 + l15) * 136 + w * 32 + quad * 8];
      *(bf16x8*)&dst[(((size_t)(ntile * 4 + w)) * 8 + es) * 512 + lane * 8] = f;
    }
  }
}

// ---------- pass A: l2c[h][m] = log2( sum_n exp2(c1 * q[n].k[m]) ) ----------
// grid (8 h, 128 mtile of 32m); 4 waves stride n-tiles; kf resident; rolling af stream.
__global__ __launch_bounds__(256, 4) void pass_a_kernel(const bf16_t* __restrict__ Qf,
                                                        const bf16_t* __restrict__ Kf,
                                                        float* __restrict__ l2c) {
  __shared__ alignas(16) float csred[4][32];
  const int t = threadIdx.x, lane = t & 63, w = t >> 6;
  const int quad = lane >> 4, l15 = lane & 15;
  const int h = blockIdx.x, mtile = blockIdx.y;
  const bf16_t* Qh = Qf + (size_t)h * 524288;
  const bf16_t* Kh = Kf + (size_t)h * 524288;
  bf16x8 kf[8];  // B-operand, 32m resident
#pragma unroll
  for (int mg = 0; mg < 2; ++mg)
#pragma unroll
    for (int ks = 0; ks < 4; ++ks)
      kf[mg * 4 + ks] = *(const bf16x8*)&Kh[((mtile * 2 + mg) * 4 + ks) * 512 + lane * 8];
  float cs0 = 0.f, cs1 = 0.f;
  uint32_t qo = w * 2048 + lane * 8;
  bf16x8 af[4];
#pragma unroll
  for (int ks = 0; ks < 4; ++ks) af[ks] = *(const bf16x8*)&Qh[qo + ks * 512];
  for (int it = 0; it < 64; ++it) {
    f32x4 c0 = {0.f, 0.f, 0.f, 0.f}, c1 = {0.f, 0.f, 0.f, 0.f};
#pragma unroll
    for (int ks = 0; ks < 4; ++ks) {
      c0 = MFMA_16x16x32(af[ks], kf[ks], c0);
      c1 = MFMA_16x16x32(af[ks], kf[4 + ks], c1);
    }
    qo += 8192;  // 4 tiles ahead (last iter overreads into Kf region: allocated, harmless)
#pragma unroll
    for (int ks = 0; ks < 4; ++ks) af[ks] = *(const bf16x8*)&Qh[qo + ks * 512];
#pragma unroll
    for (int r = 0; r < 4; ++r) {
      cs0 += EXP2(c0[r] * kC1);
      cs1 += EXP2(c1[r] * kC1);
    }
  }
  cs0 += __shfl_xor(cs0, 16, 64);
  cs0 += __shfl_xor(cs0, 32, 64);
  cs1 += __shfl_xor(cs1, 16, 64);
  cs1 += __shfl_xor(cs1, 32, 64);
  if (lane < 16) {
    csred[w][lane] = cs0;
    csred[w][16 + lane] = cs1;
  }
  __syncthreads();
  if (t < 32)
    l2c[(size_t)h * 4096 + mtile * 32 + t] =
        __builtin_log2f(csred[0][t] + csred[1][t] + csred[2][t] + csred[3][t]);
}

// ---------- pass B: z[n][e] = sum_m exp2(c1*s - l2c[m]) * v[m][e]; sigmoid; store f32 ----------
// grid (8 h, 128 ntile of 32n); waves npar(16n) x mpar(interleaved 32m strips); 16 waves/CU.
// Rolling single-buffered kf/vf (reload issued right after last read -> WAR-safe).
__global__ __launch_bounds__(256, 4) void pass_b_kernel(const bf16_t* __restrict__ Qf,
                                                        const bf16_t* __restrict__ Kf,
                                                        const bf16_t* __restrict__ Vf,
                                                        const float* __restrict__ l2c,
                                                        float* __restrict__ out) {
  __shared__ alignas(16) bf16_t sW_all[4][16][40];  // per-wave P bounce (5.1 KB)
  __shared__ alignas(16) float zred[2][2048];       // mpar merge (16 KB)
  const int t = threadIdx.x, lane = t & 63, w = t >> 6;
  const int quad = lane >> 4, l15 = lane & 15;
  const int npar = w & 1, mpar = w >> 1;
  const int h = blockIdx.x, ntile = blockIdx.y;
  const bf16_t* Qh = Qf + (size_t)h * 524288;
  const bf16_t* Kh = Kf + (size_t)h * 524288;
  const bf16_t* Vh = Vf + (size_t)h * 524288;
  const float* lb = l2c + (size_t)h * 4096;
  bf16x8 qf[4];  // B-operand q frags (col n = this wave's 16n), resident
#pragma unroll
  for (int ks = 0; ks < 4; ++ks)
    qf[ks] = *(const bf16x8*)&Qh[((ntile * 2 + npar) * 4 + ks) * 512 + lane * 8];
  uint32_t ko = mpar * 4096 + lane * 8;
  uint32_t vo = mpar * 4096 + lane * 8;
  bf16x8 kf[8];  // A-operand k frags for current 32m strip
#pragma unroll
  for (int u = 0; u < 8; ++u) kf[u] = *(const bf16x8*)&Kh[ko + u * 512];
  bf16x8 vf[8];  // B-operand v frags for current strip
#pragma unroll
  for (int es = 0; es < 8; ++es) vf[es] = *(const bf16x8*)&Vh[vo + es * 512];
  bf16_t* sW = &sW_all[w][0][0];
  f32x4 zacc[8] = {};
  for (int it = 0; it < 64; ++it) {
    const int st = it * 2 + mpar;
    f32x4 g0 = *(const f32x4*)&lb[st * 32 + quad * 4];
    f32x4 g1 = *(const f32x4*)&lb[st * 32 + 16 + quad * 4];
    f32x4 cc0 = {0.f, 0.f, 0.f, 0.f}, cc1 = {0.f, 0.f, 0.f, 0.f};
#pragma unroll
    for (int ks = 0; ks < 4; ++ks) {
      cc0 = MFMA_16x16x32(kf[ks], qf[ks], cc0);
      cc1 = MFMA_16x16x32(kf[4 + ks], qf[ks], cc1);
    }
    ko += 8192;  // next strip for this wave (st+2); tail overreads stay inside workspace
#pragma unroll
    for (int u = 0; u < 8; ++u) kf[u] = *(const bf16x8*)&Kh[ko + u * 512];
    // exp2 in C-layout (row m = ms*16+quad*4+r, col n = l15); bounce to A-layout
    bf16x4 p0, p1;
#pragma unroll
    for (int r = 0; r < 4; ++r) {
      p0[r] = (bf16_t)EXP2(cc0[r] * kC1 - g0[r]);
      p1[r] = (bf16_t)EXP2(cc1[r] * kC1 - g1[r]);
    }
    *(bf16x4*)&sW[l15 * 40 + quad * 4] = p0;
    *(bf16x4*)&sW[l15 * 40 + 16 + quad * 4] = p1;
    bf16x8 pf = *(const bf16x8*)&sW[l15 * 40 + quad * 8];  // same-wave; compiler waits lgkm
#pragma unroll
    for (int es = 0; es < 8; ++es) zacc[es] = MFMA_16x16x32(pf, vf[es], zacc[es]);
    vo += 8192;
#pragma unroll
    for (int es = 0; es < 8; ++es) vf[es] = *(const bf16x8*)&Vh[vo + es * 512];
  }
  // epilogue: merge mpar pairs via LDS, sigmoid, store f32
  __syncthreads();
  if (mpar == 1) {
#pragma unroll
    for (int es = 0; es < 8; ++es) *(f32x4*)&zred[npar][es * 256 + lane * 4] = zacc[es];
  }
  __syncthreads();
  if (mpar == 0) {
#pragma unroll
    for (int es = 0; es < 8; ++es) {
      f32x4 o = *(const f32x4*)&zred[npar][es * 256 + lane * 4];
      const int e = es * 16 + l15;
#pragma unroll
      for (int r = 0; r < 4; ++r) {
        const int n = ntile * 32 + npar * 16 + quad * 4 + r;
        const float z = zacc[es][r] + o[r];
        out[(size_t)n * 1024 + h * 128 + e] = 1.f / (1.f + EXP2(-z * kLog2e));
      }
    }
  }
}

extern "C" void kernel_launch(void* const* d_in, const int* in_sizes, int n_in, void* d_out,
                              int out_size, void* d_ws, size_t ws_size, hipStream_t stream) {
  (void)in_sizes;
  (void)n_in;
  (void)out_size;
  (void)ws_size;
  const float* X = (const float*)d_in[0];
  const float* Wq = (const float*)d_in[1];
  const float* bq = (const float*)d_in[2];
  const float* Wk = (const float*)d_in[3];
  const float* bk = (const float*)d_in[4];
  const float* Wv = (const float*)d_in[5];
  const float* bv = (const float*)d_in[6];
  float* out = (float*)d_out;
  char* ws = (char*)d_ws;
  // byte layout (39.98 MB):
  //  [0,8M):    Qf   [8M,16M): Kf   [16M,24M): Vf
  //  [24M,32M): Xb (cvt out, proj in)
  //  [32M,38M): Wt (dead after proj)
  //  [39845888,+128K): l2c
  bf16_t* Qf = (bf16_t*)(ws);
  bf16_t* Xb = (bf16_t*)(ws + 25165824);
  bf16_t* Wt = (bf16_t*)(ws + 33554432);
  float* l2c = (float*)(ws + 39845888);
  bf16_t* Kf = (bf16_t*)(ws + 8388608);
  bf16_t* Vf = (bf16_t*)(ws + 16777216);

  cvt_kernel<<<4096, 256, 0, stream>>>(X, Xb);
  transpose_f32_k<<<dim3(16, 2, 8), 256, 0, stream>>>(Wq, Wt + (size_t)0 * 8 * 131072, 1024, 128);
  transpose_f32_k<<<dim3(16, 2, 8), 256, 0, stream>>>(Wk, Wt + (size_t)1 * 8 * 131072, 1024, 128);
  transpose_f32_k<<<dim3(16, 2, 8), 256, 0, stream>>>(Wv, Wt + (size_t)2 * 8 * 131072, 1024, 128);
  proj_kernel<<<dim3(32, 24), 256, 0, stream>>>(Xb, Wt, bq, bk, bv, Qf);
  pass_a_kernel<<<dim3(8, 128), 256, 0, stream>>>(Qf, Kf, l2c);
  pass_b_kernel<<<dim3(8, 128), 256, 0, stream>>>(Qf, Kf, Vf, l2c, out);
}

// Round 7
// 248.380 us; speedup vs baseline: 1.3880x; 1.3880x over previous
//
#include <hip/hip_runtime.h>
#include <hip/hip_bf16.h>
#include <stdint.h>

typedef __bf16 bf16_t;
typedef __bf16 bf16x4 __attribute__((ext_vector_type(4)));
typedef __bf16 bf16x8 __attribute__((ext_vector_type(8)));
typedef float f32x4 __attribute__((ext_vector_type(4)));

#define MFMA_16x16x32(A, B, C) __builtin_amdgcn_mfma_f32_16x16x32_bf16(A, B, C, 0, 0, 0)
#define EXP2(x) __builtin_amdgcn_exp2f(x)

static constexpr float kScale = 0.08838834764831845f;  // 1/sqrt(128)
static constexpr float kLog2e = 1.4426950408889634f;
static constexpr float kC1 = kScale * kLog2e;  // raw-score -> exp2 argument

// async global->LDS, 16B per lane; LDS dst is wave-uniform base + lane*16
__device__ __forceinline__ void lds_cp16(void* lds, const void* g) {
  __builtin_amdgcn_global_load_lds(
      (__attribute__((address_space(1))) void*)(uintptr_t)g,
      (__attribute__((address_space(3))) void*)(uintptr_t)lds, 16, 0, 0);
}

// Stage a [R rows x K cols] bf16 tile into chunked LDS: (r,k) -> (k>>5)*(R*32)+r*32+(k&31).
template <int R, int K>
__device__ __forceinline__ void stage_tile(bf16_t* lds, const bf16_t* g, int ldg, int tid) {
  constexpr int TOT = R * K;
  constexpr int CH = R * 32;
  constexpr int ITERS = TOT / 2048;  // 256 threads * 8 elems
  const int wave = tid >> 6;
#pragma unroll
  for (int i = 0; i < ITERS; ++i) {
    int linear = i * 2048 + tid * 8;
    int chunk = linear / CH;
    int rem = linear % CH;
    int r = rem >> 5;
    int c = rem & 31;
    lds_cp16(lds + i * 2048 + wave * 512, g + r * ldg + chunk * 32 + c);
  }
}

__device__ __forceinline__ bf16x8 frag_ld(const bf16_t* lds_chunk, int row, int lane) {
  return *(const bf16x8*)(lds_chunk + row * 32 + ((lane >> 4) << 3));
}

// ---------- elementwise f32 -> bf16 convert ----------
__global__ void cvt_kernel(const float* __restrict__ src, bf16_t* __restrict__ dst) {
  const int i = (blockIdx.x * 256 + threadIdx.x) * 4;
  float4 v = *(const float4*)&src[i];
  bf16x4 o;
  o[0] = (bf16_t)v.x;
  o[1] = (bf16_t)v.y;
  o[2] = (bf16_t)v.z;
  o[3] = (bf16_t)v.w;
  *(bf16x4*)&dst[i] = o;
}

// ---------- tiled transpose f32 src -> bf16 dst: src[mats][R][C] -> dst[mats][C][R] ----------
__global__ void transpose_f32_k(const float* __restrict__ src, bf16_t* __restrict__ dst, int R,
                                int C) {
  __shared__ alignas(16) bf16_t tile[64][72];
  const int t = threadIdx.x;
  const int mat = blockIdx.z;
  const int r0 = blockIdx.x * 64, c0 = blockIdx.y * 64;
  const float* s = src + (size_t)mat * R * C;
  bf16_t* d = dst + (size_t)mat * R * C;
  const int rl = t >> 3, cl = (t & 7) * 8;
#pragma unroll
  for (int half = 0; half < 2; ++half) {
    const int r = r0 + rl + half * 32;
    float4 a = *(const float4*)&s[(size_t)r * C + c0 + cl];
    float4 b = *(const float4*)&s[(size_t)r * C + c0 + cl + 4];
    tile[cl + 0][rl + half * 32] = (bf16_t)a.x;
    tile[cl + 1][rl + half * 32] = (bf16_t)a.y;
    tile[cl + 2][rl + half * 32] = (bf16_t)a.z;
    tile[cl + 3][rl + half * 32] = (bf16_t)a.w;
    tile[cl + 4][rl + half * 32] = (bf16_t)b.x;
    tile[cl + 5][rl + half * 32] = (bf16_t)b.y;
    tile[cl + 6][rl + half * 32] = (bf16_t)b.z;
    tile[cl + 7][rl + half * 32] = (bf16_t)b.w;
  }
  __syncthreads();
  const int cl2 = t >> 3, rl2 = (t & 7) * 8;
  *(bf16x8*)&d[(size_t)(c0 + cl2) * R + r0 + rl2] = *(const bf16x8*)&tile[cl2][rl2];
  *(bf16x8*)&d[(size_t)(c0 + cl2 + 32) * R + r0 + rl2] = *(const bf16x8*)&tile[cl2 + 32][rl2];
}

// ---------- projections, writing fragment-major Qf/Kf/Vf directly ----------
// Qf/Kf: [h][nt(256)][ks(4)][lane(64)][8]  (frag = q[nt*16+l15][ks*32+quad*8+j])
// Vf:    [h][mb(128)][es(8)][lane(64)][8]  (frag = v[mb*32+quad*8+j][es*16+l15])
__global__ __launch_bounds__(256, 2) void proj_kernel(const bf16_t* __restrict__ X,
                                                      const bf16_t* __restrict__ Wt,
                                                      const float* __restrict__ bq,
                                                      const float* __restrict__ bk,
                                                      const float* __restrict__ bv,
                                                      bf16_t* __restrict__ qkv) {
  __shared__ alignas(16) char smem[34816];  // As(8K)+Bs(8K) in loop; Ct[128][136] in epilogue
  bf16_t* As = (bf16_t*)smem;
  bf16_t* Bs = (bf16_t*)(smem + 8192);
  const int t = threadIdx.x, lane = t & 63, w = t >> 6;
  const int l15 = lane & 15, quad = lane >> 4;
  const int ntile = blockIdx.x, mat = blockIdx.y;
  const bf16_t* a0 = X + (size_t)ntile * 128 * 1024;
  const bf16_t* b0 = Wt + (size_t)mat * 131072;
  f32x4 acc[4][4] = {};
  const int rb = (w >> 1) * 64, cb = (w & 1) * 64;
  for (int k0 = 0; k0 < 1024; k0 += 32) {
    stage_tile<128, 32>(As, a0 + k0, 1024, t);
    stage_tile<128, 32>(Bs, b0 + k0, 1024, t);
    __syncthreads();
    bf16x8 af[4], bfr[4];
#pragma unroll
    for (int i = 0; i < 4; ++i) af[i] = frag_ld(As, rb + i * 16 + l15, lane);
#pragma unroll
    for (int j = 0; j < 4; ++j) bfr[j] = frag_ld(Bs, cb + j * 16 + l15, lane);
#pragma unroll
    for (int i = 0; i < 4; ++i)
#pragma unroll
      for (int j = 0; j < 4; ++j) acc[i][j] = MFMA_16x16x32(af[i], bfr[j], acc[i][j]);
    __syncthreads();
  }
  const int proj = mat >> 3, h = mat & 7;
  const float* bias = (proj == 0 ? bq : proj == 1 ? bk : bv) + h * 128;
  bf16_t* Ct = (bf16_t*)smem;  // safe: loop ended with __syncthreads
  bf16_t* dst = qkv + (size_t)proj * 4194304 + (size_t)h * 524288;
  if (proj < 2) {
    // n-major bounce [n][e], pitch 136 (keeps 16B alignment, breaks pow2 stride)
#pragma unroll
    for (int i = 0; i < 4; ++i)
#pragma unroll
      for (int j = 0; j < 4; ++j) {
        const int e = cb + j * 16 + l15;
        const float bval = bias[e];
#pragma unroll
        for (int r = 0; r < 4; ++r)
          Ct[(rb + i * 16 + quad * 4 + r) * 136 + e] = (bf16_t)(acc[i][j][r] + bval);
      }
    __syncthreads();
#pragma unroll
    for (int u = 0; u < 2; ++u) {
      const int nt = w * 2 + u;
#pragma unroll
      for (int ks = 0; ks < 4; ++ks) {
        bf16x8 f = *(const bf16x8*)&Ct[(nt * 16 + l15) * 136 + ks * 32 + quad * 8];
        *(bf16x8*)&dst[(((size_t)(ntile * 8 + nt)) * 4 + ks) * 512 + lane * 8] = f;
      }
    }
  } else {
    // e-major bounce [e][m] (m = this block's n rows), b64 writes / b128 reads
#pragma unroll
    for (int i = 0; i < 4; ++i)
#pragma unroll
      for (int j = 0; j < 4; ++j) {
        const int e = cb + j * 16 + l15;
        const float bval = bias[e];
        bf16x4 pv;
#pragma unroll
        for (int r = 0; r < 4; ++r) pv[r] = (bf16_t)(acc[i][j][r] + bval);
        *(bf16x4*)&Ct[e * 136 + rb + i * 16 + quad * 4] = pv;
      }
    __syncthreads();
#pragma unroll
    for (int es = 0; es < 8; ++es) {
      bf16x8 f = *(const bf16x8*)&Ct[(es * 16 + l15) * 136 + w * 32 + quad * 8];
      *(bf16x8*)&dst[(((size_t)(ntile * 4 + w)) * 8 + es) * 512 + lane * 8] = f;
    }
  }
}

// ---------- pass A: l2c[h][m] = log2( sum_n exp2(c1 * q[n].k[m]) ) ----------
// grid (8 h, 64 mtile of 64m); kf resident (16 frags = 64 VGPR); rolling af stream.
__global__ __launch_bounds__(256, 2) void pass_a_kernel(const bf16_t* __restrict__ Qf,
                                                        const bf16_t* __restrict__ Kf,
                                                        float* __restrict__ l2c) {
  __shared__ alignas(16) float csred[4][64];
  const int t = threadIdx.x, lane = t & 63, w = t >> 6;
  const int l15 = lane & 15;
  const int h = blockIdx.x, mtile = blockIdx.y;
  const bf16_t* Qh = Qf + (size_t)h * 524288;
  const bf16_t* Kh = Kf + (size_t)h * 524288;
  bf16x8 kf[16];  // B-operand, 64m resident
#pragma unroll
  for (int mg = 0; mg < 4; ++mg)
#pragma unroll
    for (int ks = 0; ks < 4; ++ks)
      kf[mg * 4 + ks] = *(const bf16x8*)&Kh[((mtile * 4 + mg) * 4 + ks) * 512 + lane * 8];
  float cs[4] = {0.f, 0.f, 0.f, 0.f};
  uint32_t qo = w * 2048 + lane * 8;
  bf16x8 af[4];
#pragma unroll
  for (int ks = 0; ks < 4; ++ks) af[ks] = *(const bf16x8*)&Qh[qo + ks * 512];
  for (int it = 0; it < 64; ++it) {
    f32x4 c[4] = {};
#pragma unroll
    for (int ks = 0; ks < 4; ++ks)
#pragma unroll
      for (int mg = 0; mg < 4; ++mg) c[mg] = MFMA_16x16x32(af[ks], kf[mg * 4 + ks], c[mg]);
    qo += 8192;  // 4 tiles ahead (tail overreads next region: allocated, harmless)
#pragma unroll
    for (int ks = 0; ks < 4; ++ks) af[ks] = *(const bf16x8*)&Qh[qo + ks * 512];
#pragma unroll
    for (int mg = 0; mg < 4; ++mg)
#pragma unroll
      for (int r = 0; r < 4; ++r) cs[mg] += EXP2(c[mg][r] * kC1);
  }
#pragma unroll
  for (int mg = 0; mg < 4; ++mg) {
    cs[mg] += __shfl_xor(cs[mg], 16, 64);
    cs[mg] += __shfl_xor(cs[mg], 32, 64);
  }
  if (lane < 16) {
#pragma unroll
    for (int mg = 0; mg < 4; ++mg) csred[w][mg * 16 + lane] = cs[mg];
  }
  __syncthreads();
  if (t < 64)
    l2c[(size_t)h * 4096 + mtile * 64 + t] =
        __builtin_log2f(csred[0][t] + csred[1][t] + csred[2][t] + csred[3][t]);
}

// ---------- pass B: z[n][e] = sum_m exp2(c1*s - l2c[m]) * v[m][e]; sigmoid; store f32 ----------
// grid (8 h, 32 ntile of 128n), 512 threads (8 waves): npar = w&3 (32n), mpar = w>>2 (strip).
// K/V strip-pairs (64m: K 16KB + V 16KB) double-buffered in LDS via global_load_lds,
// staged once per block per iter (shared by all 8 waves); single barrier per iter (m97 style).
__global__ __launch_bounds__(512, 2) void pass_b_kernel(const bf16_t* __restrict__ Qf,
                                                        const bf16_t* __restrict__ Kf,
                                                        const bf16_t* __restrict__ Vf,
                                                        const float* __restrict__ l2c,
                                                        float* __restrict__ out) {
  __shared__ alignas(16) char smem[86016];  // [2 x 32KB kv bufs][8 x 2.5KB P-bounce]
  const int t = threadIdx.x, lane = t & 63, w = t >> 6;
  const int quad = lane >> 4, l15 = lane & 15;
  const int npar = w & 3, mpar = w >> 2;
  const int h = blockIdx.x, ntile = blockIdx.y;
  const char* KhB = (const char*)(Kf + (size_t)h * 524288);
  const char* VhB = (const char*)(Vf + (size_t)h * 524288);
  const bf16_t* Qh = Qf + (size_t)h * 524288;
  const float* lb = l2c + (size_t)h * 4096;
  bf16_t* sW = (bf16_t*)(smem + 65536) + w * 1280;  // [32n][40] bf16 per wave

  // stage pair 0 into buf 0: wave w copies K/V bytes [w*2KB, (w+1)*2KB) of the 16KB each
#pragma unroll
  for (int j = 0; j < 2; ++j) {
    const int off = (w * 2 + j) * 1024;
    lds_cp16(smem + off, KhB + off + lane * 16);
    lds_cp16(smem + 16384 + off, VhB + off + lane * 16);
  }
  // q B-operand fragments (col n = this wave's 32n), resident
  bf16x8 qf[2][4];
#pragma unroll
  for (int nsub = 0; nsub < 2; ++nsub)
#pragma unroll
    for (int ks = 0; ks < 4; ++ks)
      qf[nsub][ks] =
          *(const bf16x8*)&Qh[((ntile * 8 + npar * 2 + nsub) * 4 + ks) * 512 + lane * 8];
  f32x4 zacc[2][8] = {};
  __syncthreads();  // drains the prologue staging (vmcnt 0)

  for (int it = 0; it < 64; ++it) {
    const int cur = it & 1;
    // stage next pair into the other buffer (drains at this iter's end barrier)
    if (it < 63) {
      char* kdst = smem + (cur ^ 1) * 32768;
      const char* ksrc = KhB + (size_t)(it + 1) * 16384;
      const char* vsrc = VhB + (size_t)(it + 1) * 16384;
#pragma unroll
      for (int j = 0; j < 2; ++j) {
        const int off = (w * 2 + j) * 1024;
        lds_cp16(kdst + off, ksrc + off + lane * 16);
        lds_cp16(kdst + 16384 + off, vsrc + off + lane * 16);
      }
    }
    const int st = it * 2 + mpar;  // this wave's 32m strip
    f32x4 g0 = *(const f32x4*)&lb[st * 32 + quad * 4];
    f32x4 g1 = *(const f32x4*)&lb[st * 32 + 16 + quad * 4];
    // k A-fragments from LDS (contiguous 1KB per frag -> conflict-free b128)
    const bf16_t* kbase = (const bf16_t*)(smem + cur * 32768) + mpar * 4096;
    bf16x8 kf[8];
#pragma unroll
    for (int u = 0; u < 8; ++u) kf[u] = *(const bf16x8*)&kbase[u * 512 + lane * 8];
    // QK^T: S^T tile [32m][32n]
    f32x4 cc[2][2] = {};
#pragma unroll
    for (int ks = 0; ks < 4; ++ks)
#pragma unroll
      for (int ms = 0; ms < 2; ++ms)
#pragma unroll
        for (int nsub = 0; nsub < 2; ++nsub)
          cc[ms][nsub] = MFMA_16x16x32(kf[ms * 4 + ks], qf[nsub][ks], cc[ms][nsub]);
    // exp2 in C-layout (row m = ms*16+quad*4+r, col n = nsub*16+l15); bounce to A-layout
#pragma unroll
    for (int ms = 0; ms < 2; ++ms) {
      const f32x4 g = ms ? g1 : g0;
#pragma unroll
      for (int nsub = 0; nsub < 2; ++nsub) {
        bf16x4 pv;
#pragma unroll
        for (int r = 0; r < 4; ++r) pv[r] = (bf16_t)EXP2(cc[ms][nsub][r] * kC1 - g[r]);
        *(bf16x4*)&sW[(nsub * 16 + l15) * 40 + ms * 16 + quad * 4] = pv;
      }
    }
    bf16x8 pf[2];  // P A-frags (same-wave data; compiler inserts lgkm wait)
#pragma unroll
    for (int nsub = 0; nsub < 2; ++nsub)
      pf[nsub] = *(const bf16x8*)&sW[(nsub * 16 + l15) * 40 + quad * 8];
    // PV from LDS v strip
    const bf16_t* vbase = (const bf16_t*)(smem + cur * 32768 + 16384) + mpar * 4096;
#pragma unroll
    for (int es = 0; es < 8; ++es) {
      bf16x8 vf = *(const bf16x8*)&vbase[es * 512 + lane * 8];
#pragma unroll
      for (int nsub = 0; nsub < 2; ++nsub)
        zacc[nsub][es] = MFMA_16x16x32(pf[nsub], vf, zacc[nsub][es]);
    }
    __syncthreads();  // all reads of cur done + staged writes to nxt arrived
  }
  // epilogue: merge mpar pairs via LDS (reuse kv buffers), sigmoid, store f32
  float* red = (float*)smem;  // [npar][nsub*8+es][lane*4] = 16KB per npar
  if (mpar == 1) {
#pragma unroll
    for (int nsub = 0; nsub < 2; ++nsub)
#pragma unroll
      for (int es = 0; es < 8; ++es)
        *(f32x4*)&red[npar * 4096 + (nsub * 8 + es) * 256 + lane * 4] = zacc[nsub][es];
  }
  __syncthreads();
  if (mpar == 0) {
#pragma unroll
    for (int nsub = 0; nsub < 2; ++nsub) {
#pragma unroll
      for (int es = 0; es < 8; ++es) {
        f32x4 o = *(const f32x4*)&red[npar * 4096 + (nsub * 8 + es) * 256 + lane * 4];
        const int e = es * 16 + l15;
#pragma unroll
        for (int r = 0; r < 4; ++r) {
          const int n = ntile * 128 + npar * 32 + nsub * 16 + quad * 4 + r;
          const float z = zacc[nsub][es][r] + o[r];
          out[(size_t)n * 1024 + h * 128 + e] = 1.f / (1.f + EXP2(-z * kLog2e));
        }
      }
    }
  }
}

extern "C" void kernel_launch(void* const* d_in, const int* in_sizes, int n_in, void* d_out,
                              int out_size, void* d_ws, size_t ws_size, hipStream_t stream) {
  (void)in_sizes;
  (void)n_in;
  (void)out_size;
  (void)ws_size;
  const float* X = (const float*)d_in[0];
  const float* Wq = (const float*)d_in[1];
  const float* bq = (const float*)d_in[2];
  const float* Wk = (const float*)d_in[3];
  const float* bk = (const float*)d_in[4];
  const float* Wv = (const float*)d_in[5];
  const float* bv = (const float*)d_in[6];
  float* out = (float*)d_out;
  char* ws = (char*)d_ws;
  // byte layout (39.98 MB):
  //  [0,8M): Qf   [8M,16M): Kf   [16M,24M): Vf
  //  [24M,32M): Xb (cvt out, proj in)
  //  [32M,38M): Wt (dead after proj)
  //  [39845888,+128K): l2c
  bf16_t* Qf = (bf16_t*)(ws);
  bf16_t* Kf = (bf16_t*)(ws + 8388608);
  bf16_t* Vf = (bf16_t*)(ws + 16777216);
  bf16_t* Xb = (bf16_t*)(ws + 25165824);
  bf16_t* Wt = (bf16_t*)(ws + 33554432);
  float* l2c = (float*)(ws + 39845888);

  cvt_kernel<<<4096, 256, 0, stream>>>(X, Xb);
  transpose_f32_k<<<dim3(16, 2, 8), 256, 0, stream>>>(Wq, Wt + (size_t)0 * 8 * 131072, 1024, 128);
  transpose_f32_k<<<dim3(16, 2, 8), 256, 0, stream>>>(Wk, Wt + (size_t)1 * 8 * 131072, 1024, 128);
  transpose_f32_k<<<dim3(16, 2, 8), 256, 0, stream>>>(Wv, Wt + (size_t)2 * 8 * 131072, 1024, 128);
  proj_kernel<<<dim3(32, 24), 256, 0, stream>>>(Xb, Wt, bq, bk, bv, Qf);
  pass_a_kernel<<<dim3(8, 64), 256, 0, stream>>>(Qf, Kf, l2c);
  pass_b_kernel<<<dim3(8, 32), 512, 0, stream>>>(Qf, Kf, Vf, l2c, out);
}